// Round 2
// baseline (271.642 us; speedup 1.0000x reference)
//
#include <hip/hip_runtime.h>

// LSTM B=65536, L=6, H=50, T=3, IN=3, FC 50->1 — fp16 MFMA, R9.
//
// R9 vs R8 (148us kernel: VALUBusy 43%, MfmaUtil 17%, >50% pipe-idle from
// phase-ordered step body under barrier lockstep):
//  - Fine-grained software pipeline of the step body, per m-tile, 2-deep:
//      preload Hf(mt+1) -> M4(mt) -> ACT(mt-1); XM(mt-1) -> preload Xn(mt+1)
//    so ds_read / MFMA / transcendental issue interleave at ~100-cycle
//    granularity inside each wave instead of monolithic phases. The act-trans
//    burst of tile mt-1 overlaps M4(mt)'s MFMAs; x-prefetch reads hide under
//    the trans. ACT/XM expanded via macros (static acc indexing, no scratch).
//  - Numerics bitwise-identical to R8 (same MFMA accumulation order, same
//    activation ops per value).
// Layout unchanged: gates^T = W*X^T, n = 4j+gate; lane holds all 4 gates of
// unit j = 4*ntg+q (lane-local c/h update). One barrier per step.

namespace {

constexpr int H  = 50;
constexpr int L  = 6;
constexpr int T  = 3;
constexpr int IN = 3;
constexpr int M  = 64;     // samples per block (4 m-tiles)
constexpr int BLK = 512;   // 8 waves
constexpr int ROWS = 72;   // _Float16 row stride (144 B)

using half8  = __attribute__((ext_vector_type(8))) _Float16;
using half2v = __attribute__((ext_vector_type(2))) _Float16;
using f32x4  = __attribute__((ext_vector_type(4))) float;

__device__ __forceinline__ float rcp_(float x) { return __builtin_amdgcn_rcpf(x); }
__device__ __forceinline__ float ex2(float x)  { return __builtin_amdgcn_exp2f(x); }

// ---------------- prologue: pack fp16 A-fragments, prescaled ----------------
// frag id f = (l*4 + s)*16 + nt ; lane's frag: W[n=16*nt+(lam&15)][k=32*s+(lam>>4)*8+jj]
// Rows prescaled: gate g (n&3==2) by 2/ln2, others by 1/ln2 (bias included).
__global__ void wprep(const float* __restrict__ w_ih0, const float* __restrict__ w_ihL,
                      const float* __restrict__ w_hh,  const float* __restrict__ b_ih,
                      const float* __restrict__ b_hh,  _Float16* __restrict__ wbuf) {
  int t = blockIdx.x * 256 + threadIdx.x;
  if (t >= 384 * 64) return;
  int lam = t & 63, f = t >> 6;
  int nt = f & 15, s = (f >> 4) & 3, l = f >> 6;
  int n = nt * 16 + (lam & 15);
  int j = n >> 2, gate = n & 3, row = gate * 50 + j;  // PyTorch gate order i,f,g,o
  float scale = (gate == 2) ? 2.8853900817779268f : 1.4426950408889634f;
  _Float16 o8[8];
#pragma unroll
  for (int jj = 0; jj < 8; ++jj) {
    int k = s * 32 + (lam >> 4) * 8 + jj;
    float v = 0.f;
    if (j < H) {
      if (s < 2) {                       // x-part, k in [0,64)
        int ksz = (l == 0) ? IN : H;
        if (k < ksz) v = (l == 0) ? w_ih0[row * IN + k]
                                  : w_ihL[((size_t)(l - 1) * 200 + row) * H + k];
      } else {                           // h-part
        int kh = k - 64;
        if (kh < H)        v = w_hh[((size_t)l * 200 + row) * H + kh];
        else if (kh == 63) v = b_ih[l * 200 + row] + b_hh[l * 200 + row];  // bias
      }
    }
    o8[jj] = (_Float16)(v * scale);
  }
  ((half8*)wbuf)[t] = *(half8*)o8;
}

// ---------------- main kernel ----------------
__global__ __launch_bounds__(BLK, 4)   // cap 128 combined regs -> 2 blocks/CU
void lstm_mfma(const float* __restrict__ x,   const float* __restrict__ h0,
               const float* __restrict__ c0,  const float* __restrict__ fc_w,
               const float* __restrict__ fc_b, const _Float16* __restrict__ wbuf,
               float* __restrict__ out, int B) {
  const int tid = threadIdx.x;
  const int lam = tid & 63;
  const int q   = lam >> 4;
  const int lm  = lam & 15;
  const int bbase = blockIdx.x * M;
  const int ng  = __builtin_amdgcn_readfirstlane(tid >> 6);
  const int ntp = __builtin_amdgcn_readfirstlane((ng + blockIdx.x) & 7);  // pad-wave rotation
  const int ntg0 = 2 * ntp, ntg1 = 2 * ntp + 1;
  const bool live0 = (ntg0 <= 12);          // tiles 13..15 are pure padding (j>=52)
  const bool live1 = (ntg1 <= 12);

  __shared__ __align__(16) _Float16 ys[2][T][M][ROWS];

  // ---- staging: x pairs k<4 + zeros k[4,32) into ys[0]; k[50,64) consts into
  //      all 6 slots (written once; h-writes/h0-stage never touch k>=50) ----
  if (tid < T * M) {                         // 192 threads, one (t,m) row each
    const int t = tid >> 6, m = tid & 63;
    const float* xs = x + (size_t)(bbase + m) * (IN * T) + t;
    _Float16* row = &ys[0][t][m][0];
    half2v p0; p0[0] = (_Float16)xs[0]; p0[1] = (_Float16)xs[3];
    half2v p1; p1[0] = (_Float16)xs[6]; p1[1] = (_Float16)0.f;
    *(half2v*)(row)     = p0;
    *(half2v*)(row + 2) = p1;
#pragma unroll
    for (int z = 0; z < 7; ++z)              // k in [4,32) := 0 (layer-0 slab 0 pad)
      *(unsigned long long*)(row + 4 + 4 * z) = 0ull;
  }
  if (tid < 2 * T * M) {                     // 384 rows: k in [50,64) pad + bias col
    _Float16* row = &ys[0][0][0][0] + (size_t)tid * ROWS;
#pragma unroll
    for (int z = 0; z < 6; ++z)
      *(unsigned int*)(row + 50 + 2 * z) = 0u;
    half2v pb; pb[0] = (_Float16)0.f; pb[1] = (_Float16)1.f;   // k63 = 1.0 (bias)
    *(half2v*)(row + 62) = pb;
  }
  __syncthreads();

  float cc[2][4];
  f32x4 xa[2][4];                            // x-part acc, h-part accumulates in
  half8 W[2][4];                             // [nt][kslab] — 32 regs
  const f32x4 z4 = {0.f, 0.f, 0.f, 0.f};

  for (int l = 0; l < L; ++l) {
    const int sb = l & 1, db = sb ^ 1;
    _Float16 (*src)[M][ROWS] = ys[sb];
    _Float16 (*dst)[M][ROWS] = ys[db];

    // ---- c0 straight to registers (dead tiles skipped) ----
#pragma unroll
    for (int nt = 0; nt < 2; ++nt) {
      const int ntg = nt ? ntg1 : ntg0;
      const bool lv = nt ? live1 : live0;
      const int j = 4 * ntg + q;
#pragma unroll
      for (int mt = 0; mt < 4; ++mt)
        cc[nt][mt] = (lv && j < H)
            ? c0[((size_t)l * B + bbase + mt * 16 + lm) * H + j] : 0.f;
    }
    // ---- W fragments for this layer (live tiles only, coalesced dwordx4) ----
#pragma unroll
    for (int nt = 0; nt < 2; ++nt) {
      const int ntg = nt ? ntg1 : ntg0;
      const bool lv = nt ? live1 : live0;
      if (lv)
#pragma unroll
        for (int s = 0; s < 4; ++s)
          W[nt][s] = ((const half8*)wbuf)[((l * 4 + s) * 16 + ntg) * 64 + lam];
    }

    // ---- x-part of t=0 (src stable since prev barrier; overlaps h0 staging) --
    if (live0) {
#pragma unroll
      for (int s = 0; s < 2; ++s) {
        if (s == 1 && l == 0) continue;       // W==0 slab (and avoids uninit LDS)
        half8 Xf[4];
#pragma unroll
        for (int mt = 0; mt < 4; ++mt)
          Xf[mt] = *(const half8*)(&src[0][mt * 16 + lm][s * 32 + q * 8]);
#pragma unroll
        for (int mt = 0; mt < 4; ++mt)
          xa[0][mt] = __builtin_amdgcn_mfma_f32_16x16x32_f16(
              W[0][s], Xf[mt], s == 0 ? z4 : xa[0][mt], 0, 0, 0);
        if (live1)
#pragma unroll
          for (int mt = 0; mt < 4; ++mt)
            xa[1][mt] = __builtin_amdgcn_mfma_f32_16x16x32_f16(
                W[1][s], Xf[mt], s == 0 ? z4 : xa[1][mt], 0, 0, 0);
      }
    }

    // ---- stage h0 into dst[T-1], pair-packed (k<50; k>=50 is invariant) ----
    {
      const int mg = tid >> 3, kpl = tid & 7;             // 8 threads per row
      const float* hp = h0 + ((size_t)l * B + bbase + mg) * H + 2 * kpl;
      _Float16* dp = &dst[T - 1][mg][2 * kpl];
#pragma unroll
      for (int it = 0; it < 4; ++it) {
        if (it < 3 || kpl == 0) {                         // kp = kpl+8it < 25
          float2 v = *(const float2*)(hp + 16 * it);
          half2v pv; pv[0] = (_Float16)v.x; pv[1] = (_Float16)v.y;
          *(half2v*)(dp + 16 * it) = pv;
        }
      }
    }
    __syncthreads();

// ---- per-mt macros (literal args -> static acc indexing, rule #20) ----
#define LD_H(s, mt) (*(const half8*)(&dst[hsl][(mt) * 16 + lm][(s) * 32 + q * 8]))
#define LD_X(s, mt) (*(const half8*)(&src[t + 1][(mt) * 16 + lm][(s) * 32 + q * 8]))
#define ACT1(nt, mt) do {                                                      \
    const int j_ = 4 * ((nt) ? ntg1 : ntg0) + q;                               \
    const float ig = rcp_(1.f + ex2(-xa[nt][mt][0]));                          \
    const float fg = rcp_(1.f + ex2(-xa[nt][mt][1]));                          \
    const float gg = 2.f * rcp_(1.f + ex2(-xa[nt][mt][2])) - 1.f;              \
    const float og = rcp_(1.f + ex2(-xa[nt][mt][3]));                          \
    const float cv = fg * cc[nt][mt] + ig * gg;                                \
    cc[nt][mt] = cv;                                                           \
    const float tc = 2.f * rcp_(1.f + ex2(-2.8853900817779268f * cv)) - 1.f;   \
    const float hv = og * tc;                                                  \
    if (j_ < H) dst[t][(mt) * 16 + lm][j_] = (_Float16)hv;                     \
  } while (0)
#define XM1(nt, mt) do {                                                       \
    xa[nt][mt] = __builtin_amdgcn_mfma_f32_16x16x32_f16(                       \
        W[nt][0], Xn[0][(mt) & 1], z4, 0, 0, 0);                               \
    if (l > 0)                                                                 \
      xa[nt][mt] = __builtin_amdgcn_mfma_f32_16x16x32_f16(                     \
          W[nt][1], Xn[1][(mt) & 1], xa[nt][mt], 0, 0, 0);                     \
  } while (0)
#define STEP_TAIL(mt) do {                                                     \
    ACT1(0, mt);                                                               \
    if (live1) ACT1(1, mt);                                                    \
    if (pre) { XM1(0, mt); if (live1) XM1(1, mt); }                            \
  } while (0)

#pragma unroll
    for (int t = 0; t < T; ++t) {
      const int hsl = (t == 0) ? T - 1 : t - 1;           // h-source slot in dst buf
      if (live0) {                                        // all-dead wave skips compute
        const bool pre = (t < T - 1);
        half8 Hf[2][2], Xn[2][2];
        // preload mt=0 fragments (h-part just became visible; x(t+1) is stable)
        Hf[0][0] = LD_H(0, 0);
        Hf[1][0] = LD_H(1, 0);
        if (pre) {
          Xn[0][0] = LD_X(0, 0);
          if (l > 0) Xn[1][0] = LD_X(1, 0);
        }
#pragma unroll
        for (int mt = 0; mt < 4; ++mt) {
          const int cur = mt & 1, nxt = cur ^ 1;
          if (mt < 3) {                                   // preload h-frags mt+1
            Hf[0][nxt] = LD_H(0, mt + 1);
            Hf[1][nxt] = LD_H(1, mt + 1);
          }
          // M4(mt): h-part accumulates onto prefetched x-part
          xa[0][mt] = __builtin_amdgcn_mfma_f32_16x16x32_f16(
              W[0][2], Hf[0][cur], xa[0][mt], 0, 0, 0);
          xa[0][mt] = __builtin_amdgcn_mfma_f32_16x16x32_f16(
              W[0][3], Hf[1][cur], xa[0][mt], 0, 0, 0);
          if (live1) {
            xa[1][mt] = __builtin_amdgcn_mfma_f32_16x16x32_f16(
                W[1][2], Hf[0][cur], xa[1][mt], 0, 0, 0);
            xa[1][mt] = __builtin_amdgcn_mfma_f32_16x16x32_f16(
                W[1][3], Hf[1][cur], xa[1][mt], 0, 0, 0);
          }
          // act + x-prefetch for tile mt-1 (its M4 has fully drained);
          // trans burst here overlaps M4(mt)'s MFMAs in flight
          if (mt > 0) STEP_TAIL(mt - 1);
          // x(t+1) frags for mt+1 (slot (mt+1)&1 freed by XM1 in STEP_TAIL)
          if (mt < 3 && pre) {
            Xn[0][nxt] = LD_X(0, mt + 1);
            if (l > 0) Xn[1][nxt] = LD_X(1, mt + 1);
          }
        }
        STEP_TAIL(3);
      }
      __syncthreads();   // h_t (and, at t=T-1, layer output) visible
    }
#undef LD_H
#undef LD_X
#undef ACT1
#undef XM1
#undef STEP_TAIL
  }

  // ---- fc tail: out[b] = fc_w · h_last + fc_b ; final dst buffer = ys[0] ----
  {
    int m = tid >> 3, strip = tid & 7;
    float part = 0.f;
#pragma unroll
    for (int jj = 0; jj < 7; ++jj) {
      int j = strip + 8 * jj;
      if (j < H) part += fc_w[j] * (float)ys[0][T - 1][m][j];
    }
    part += __shfl_xor(part, 4);
    part += __shfl_xor(part, 2);
    part += __shfl_xor(part, 1);
    if (strip == 0) out[bbase + m] = part + fc_b[0];
  }
}

}  // namespace

extern "C" void kernel_launch(void* const* d_in, const int* in_sizes, int n_in,
                              void* d_out, int out_size, void* d_ws, size_t ws_size,
                              hipStream_t stream) {
  const float* x     = (const float*)d_in[0];
  const float* h0    = (const float*)d_in[1];
  const float* c0    = (const float*)d_in[2];
  const float* w_ih0 = (const float*)d_in[3];
  const float* w_ih  = (const float*)d_in[4];
  const float* w_hh  = (const float*)d_in[5];
  const float* b_ih  = (const float*)d_in[6];
  const float* b_hh  = (const float*)d_in[7];
  const float* fc_w  = (const float*)d_in[8];
  const float* fc_b  = (const float*)d_in[9];
  float* out         = (float*)d_out;

  const int B = in_sizes[0] / (IN * T);  // 65536
  _Float16* wbuf = (_Float16*)d_ws;      // 384 frags * 64 lanes * 16 B = 393 KB

  wprep<<<(384 * 64 + 255) / 256, 256, 0, stream>>>(w_ih0, w_ih, w_hh, b_ih, b_hh, wbuf);
  lstm_mfma<<<B / M, BLK, 0, stream>>>(x, h0, c0, fc_w, fc_b, wbuf, out, B);
}

// Round 3
// 268.053 us; speedup vs baseline: 1.0134x; 1.0134x over previous
//
#include <hip/hip_runtime.h>

// LSTM B=65536, L=6, H=50, T=3, IN=3, FC 50->1 — fp16 MFMA, R10.
//
// R10 vs R8 (148us; R9's manual pipeline spilled -> reverted):
//  - Occupancy attack: R8 is issue-starved (VALU 43% + MFMA 17%, ~40% barrier
//    wait) at 16 waves/CU (LDS-capped, 55.3KB x 2 blocks).
//  - LDS ring: ping-pong ys[2][T] -> 5-slot ring. sigma(l,t)=(4l+t+1)%5,
//    h0 slot (4l)%5, x staged in slots 2,3,4. Liveness: h_t of layer l is
//    last read by layer l+1's step-(t-1) prefetch -> all reuses barrier-
//    separated; same-interval slots distinct (verified t=0,1,2). 55.3->46KB.
//  - Register attack: 8 waves x 2 n-tiles -> 16 waves x 1 n-tile (BLK=1024).
//    Persistent state halves (W 32->16, xa 32->16, cc 8->4); B-frags have no
//    reuse -> stream 2-deep. launch_bounds(1024,8) caps 64 regs ->
//    2 blocks x 16 waves = 32 waves/CU (8/SIMD), 2x R8's occupancy.
//  - Inner loop = R8's proven monolithic phases (h-MFMA -> ACT -> x-prefetch),
//    same accumulation order -> bitwise-identical numerics.
// Layout: gates^T = W*X^T, n = 4j+gate; lane holds all 4 gates of unit
// j = 4*ntg+q (lane-local c/h update). One barrier per step + 1 per layer.

namespace {

constexpr int H  = 50;
constexpr int L  = 6;
constexpr int T  = 3;
constexpr int IN = 3;
constexpr int M  = 64;     // samples per block (4 m-tiles)
constexpr int BLK = 1024;  // 16 waves, 1 n-tile each
constexpr int ROWS = 72;   // _Float16 row stride (144 B)
constexpr int NSLOT = 5;   // LDS ring slots

using half8  = __attribute__((ext_vector_type(8))) _Float16;
using half2v = __attribute__((ext_vector_type(2))) _Float16;
using f32x4  = __attribute__((ext_vector_type(4))) float;

__device__ __forceinline__ float rcp_(float x) { return __builtin_amdgcn_rcpf(x); }
__device__ __forceinline__ float ex2(float x)  { return __builtin_amdgcn_exp2f(x); }

// ---------------- prologue: pack fp16 A-fragments, prescaled ----------------
// frag id f = (l*4 + s)*16 + nt ; lane's frag: W[n=16*nt+(lam&15)][k=32*s+(lam>>4)*8+jj]
// Rows prescaled: gate g (n&3==2) by 2/ln2, others by 1/ln2 (bias included).
__global__ void wprep(const float* __restrict__ w_ih0, const float* __restrict__ w_ihL,
                      const float* __restrict__ w_hh,  const float* __restrict__ b_ih,
                      const float* __restrict__ b_hh,  _Float16* __restrict__ wbuf) {
  int t = blockIdx.x * 256 + threadIdx.x;
  if (t >= 384 * 64) return;
  int lam = t & 63, f = t >> 6;
  int nt = f & 15, s = (f >> 4) & 3, l = f >> 6;
  int n = nt * 16 + (lam & 15);
  int j = n >> 2, gate = n & 3, row = gate * 50 + j;  // PyTorch gate order i,f,g,o
  float scale = (gate == 2) ? 2.8853900817779268f : 1.4426950408889634f;
  _Float16 o8[8];
#pragma unroll
  for (int jj = 0; jj < 8; ++jj) {
    int k = s * 32 + (lam >> 4) * 8 + jj;
    float v = 0.f;
    if (j < H) {
      if (s < 2) {                       // x-part, k in [0,64)
        int ksz = (l == 0) ? IN : H;
        if (k < ksz) v = (l == 0) ? w_ih0[row * IN + k]
                                  : w_ihL[((size_t)(l - 1) * 200 + row) * H + k];
      } else {                           // h-part
        int kh = k - 64;
        if (kh < H)        v = w_hh[((size_t)l * 200 + row) * H + kh];
        else if (kh == 63) v = b_ih[l * 200 + row] + b_hh[l * 200 + row];  // bias
      }
    }
    o8[jj] = (_Float16)(v * scale);
  }
  ((half8*)wbuf)[t] = *(half8*)o8;
}

// ---------------- main kernel ----------------
__global__ __launch_bounds__(BLK, 8)   // 8 waves/EU -> cap 64 regs, 2 blocks/CU
void lstm_mfma(const float* __restrict__ x,   const float* __restrict__ h0,
               const float* __restrict__ c0,  const float* __restrict__ fc_w,
               const float* __restrict__ fc_b, const _Float16* __restrict__ wbuf,
               float* __restrict__ out, int B) {
  const int tid = threadIdx.x;
  const int lam = tid & 63;
  const int q   = lam >> 4;
  const int lm  = lam & 15;
  const int bbase = blockIdx.x * M;
  const int w   = __builtin_amdgcn_readfirstlane(tid >> 6);
  const int ntg = __builtin_amdgcn_readfirstlane((w + blockIdx.x) & 15);  // pad-wave rotation
  const bool live = (ntg <= 12);            // tiles 13..15 are pure padding (j>=52)
  const int j = 4 * ntg + q;                // unit index this lane owns (gates in acc regs)

  __shared__ __align__(16) _Float16 ys[NSLOT][M][ROWS];   // 46080 B

  // ---- once-only invariant: cols [50,62]=0, col 63=1.0 in ALL slots.
  //      (h-writes touch j<50 only; h0/x staging touch k<50 -> holds forever)
  if (tid < NSLOT * M) {
    _Float16* row = &ys[0][0][0] + (size_t)tid * ROWS;
#pragma unroll
    for (int z = 0; z < 6; ++z)
      *(unsigned int*)(row + 50 + 2 * z) = 0u;            // cols 50..61
    half2v pb; pb[0] = (_Float16)0.f; pb[1] = (_Float16)1.f;
    *(half2v*)(row + 62) = pb;                            // 62=0, 63=1.0
  }
  // ---- x staging into slots 2,3,4 (= sigma(-1,t)): k<3 data, [3,32) zero ----
  if (tid < T * M) {
    const int t = tid >> 6, m = tid & 63;
    const float* xs = x + (size_t)(bbase + m) * (IN * T) + t;
    _Float16* row = &ys[2 + t][m][0];
    half2v p0; p0[0] = (_Float16)xs[0]; p0[1] = (_Float16)xs[3];
    half2v p1; p1[0] = (_Float16)xs[6]; p1[1] = (_Float16)0.f;
    *(half2v*)(row)     = p0;
    *(half2v*)(row + 2) = p1;
#pragma unroll
    for (int z = 0; z < 7; ++z)              // k in [4,32) := 0 (layer-0 slab-0 pad)
      *(unsigned long long*)(row + 4 + 4 * z) = 0ull;
  }
  __syncthreads();

  float cc[4];
  f32x4 xa[4];                               // x-part acc; h-part accumulates in
  half8 W4[4];                               // 4 k-slabs — 16 regs
  const f32x4 z4 = {0.f, 0.f, 0.f, 0.f};
  int b = 0;                                 // h0 slot for layer l = (4l)%5

  for (int l = 0; l < L; ++l) {
    const int sh0 = b;
    int s1 = b + 1; if (s1 >= NSLOT) s1 -= NSLOT;   // out[0]
    int s2 = b + 2; if (s2 >= NSLOT) s2 -= NSLOT;   // out[1] = x[0]
    int s3 = b + 3; if (s3 >= NSLOT) s3 -= NSLOT;   // out[2] = x[1]
    int s4 = b + 4; if (s4 >= NSLOT) s4 -= NSLOT;   // x[2]

    if (live) {
      // ---- c0 straight to registers ----
#pragma unroll
      for (int mt = 0; mt < 4; ++mt)
        cc[mt] = (j < H)
            ? c0[((size_t)l * B + bbase + mt * 16 + lm) * H + j] : 0.f;
      // ---- W fragments for this layer (coalesced dwordx4) ----
#pragma unroll
      for (int s = 0; s < 4; ++s)
        W4[s] = ((const half8*)wbuf)[((l * 4 + s) * 16 + ntg) * 64 + lam];
      // ---- x-part of t=0 from x[0]=s2 (stable since prev barrier) ----
#pragma unroll
      for (int mt = 0; mt < 4; ++mt) {
        half8 X0 = *(const half8*)(&ys[s2][mt * 16 + lm][q * 8]);
        xa[mt] = __builtin_amdgcn_mfma_f32_16x16x32_f16(W4[0], X0, z4, 0, 0, 0);
      }
      if (l > 0) {                           // layer-0 slab 1 is all-zero W: skip
#pragma unroll
        for (int mt = 0; mt < 4; ++mt) {
          half8 X1 = *(const half8*)(&ys[s2][mt * 16 + lm][32 + q * 8]);
          xa[mt] = __builtin_amdgcn_mfma_f32_16x16x32_f16(W4[1], X1, xa[mt], 0, 0, 0);
        }
      }
    }
    // ---- stage h0 into slot sh0, pair-packed, all 1024 threads ----
    {
      const int mg = tid >> 4, kpl = tid & 15;           // 16 threads per row
      const float* hp = h0 + ((size_t)l * B + bbase + mg) * H + 2 * kpl;
      _Float16* dp = &ys[sh0][mg][2 * kpl];
      float2 v = *(const float2*)(hp);
      half2v pv; pv[0] = (_Float16)v.x; pv[1] = (_Float16)v.y;
      *(half2v*)dp = pv;
      if (kpl < 9) {                                     // pairs 16..24 (k 32..49)
        float2 v2 = *(const float2*)(hp + 32);
        half2v p2; p2[0] = (_Float16)v2.x; p2[1] = (_Float16)v2.y;
        *(half2v*)(dp + 32) = p2;
      }
    }
    __syncthreads();

#pragma unroll
    for (int t = 0; t < T; ++t) {
      const int shs = (t == 0) ? sh0 : ((t == 1) ? s1 : s2);  // h-source slot
      const int sot = (t == 0) ? s1  : ((t == 1) ? s2 : s3);  // h-dest slot
      const int sxt = (t == 0) ? s3  : s4;                    // x-prefetch slot
      if (live) {
        // ---- h-part: slabs 2,3 accumulate onto prefetched x-part ----
#pragma unroll
        for (int s = 0; s < 2; ++s)
#pragma unroll
          for (int mt = 0; mt < 4; ++mt) {
            half8 Hf = *(const half8*)(&ys[shs][mt * 16 + lm][s * 32 + q * 8]);
            xa[mt] = __builtin_amdgcn_mfma_f32_16x16x32_f16(W4[2 + s], Hf, xa[mt], 0, 0, 0);
          }
        // ---- activations: prescaled gates -> sigm = rcp(1+exp2(-g)) ----
#pragma unroll
        for (int mt = 0; mt < 4; ++mt) {
          const float ig = rcp_(1.f + ex2(-xa[mt][0]));
          const float fg = rcp_(1.f + ex2(-xa[mt][1]));
          const float gg = 2.f * rcp_(1.f + ex2(-xa[mt][2])) - 1.f;
          const float og = rcp_(1.f + ex2(-xa[mt][3]));
          const float cv = fg * cc[mt] + ig * gg;
          cc[mt] = cv;
          const float tc = 2.f * rcp_(1.f + ex2(-2.8853900817779268f * cv)) - 1.f;
          if (j < H)                          // pad cols (and k63=1.0) stay intact
            ys[sot][mt * 16 + lm][j] = (_Float16)(og * tc);
        }
        // ---- x-part prefetch for t+1 (slot stable; fills barrier window) ----
        if (t < T - 1) {
#pragma unroll
          for (int mt = 0; mt < 4; ++mt) {
            half8 X0 = *(const half8*)(&ys[sxt][mt * 16 + lm][q * 8]);
            xa[mt] = __builtin_amdgcn_mfma_f32_16x16x32_f16(W4[0], X0, z4, 0, 0, 0);
          }
          if (l > 0) {
#pragma unroll
            for (int mt = 0; mt < 4; ++mt) {
              half8 X1 = *(const half8*)(&ys[sxt][mt * 16 + lm][32 + q * 8]);
              xa[mt] = __builtin_amdgcn_mfma_f32_16x16x32_f16(W4[1], X1, xa[mt], 0, 0, 0);
            }
          }
        }
      }
      __syncthreads();   // h_t (and, at t=T-1, layer output) visible
    }
    b = (b == 0) ? (NSLOT - 1) : b - 1;      // (4(l+1))%5 = (b+4)%5 = b-1 mod 5
  }

  // ---- fc tail: out[b] = fc_w · h_last + fc_b ----
  // final h slot = sigma(L-1, T-1) = (4*(L-1)+T)%5 = (20+3)%5 = 3
  if (tid < 512) {
    int m = tid >> 3, strip = tid & 7;
    float part = 0.f;
#pragma unroll
    for (int jj = 0; jj < 7; ++jj) {
      int jf = strip + 8 * jj;
      if (jf < H) part += fc_w[jf] * (float)ys[3][m][jf];
    }
    part += __shfl_xor(part, 4);
    part += __shfl_xor(part, 2);
    part += __shfl_xor(part, 1);
    if (strip == 0) out[bbase + m] = part + fc_b[0];
  }
}

}  // namespace

extern "C" void kernel_launch(void* const* d_in, const int* in_sizes, int n_in,
                              void* d_out, int out_size, void* d_ws, size_t ws_size,
                              hipStream_t stream) {
  const float* x     = (const float*)d_in[0];
  const float* h0    = (const float*)d_in[1];
  const float* c0    = (const float*)d_in[2];
  const float* w_ih0 = (const float*)d_in[3];
  const float* w_ih  = (const float*)d_in[4];
  const float* w_hh  = (const float*)d_in[5];
  const float* b_ih  = (const float*)d_in[6];
  const float* b_hh  = (const float*)d_in[7];
  const float* fc_w  = (const float*)d_in[8];
  const float* fc_b  = (const float*)d_in[9];
  float* out         = (float*)d_out;

  const int B = in_sizes[0] / (IN * T);  // 65536
  _Float16* wbuf = (_Float16*)d_ws;      // 384 frags * 64 lanes * 16 B = 393 KB

  wprep<<<(384 * 64 + 255) / 256, 256, 0, stream>>>(w_ih0, w_ih, w_hh, b_ih, b_hh, wbuf);
  lstm_mfma<<<B / M, BLK, 0, stream>>>(x, h0, c0, fc_w, fc_b, wbuf, out, B);
}